// Round 5
// baseline (219.704 us; speedup 1.0000x reference)
//
#include <hip/hip_runtime.h>
#include <math.h>

// Problem constants
#define NB    64
#define CC    256
#define TT    64
#define VV    25
#define HID   16
#define NG    5
#define ROWF  1600          // floats per (n,c) pair = T*V
#define ROWF4 400           // float4 per (n,c) pair
#define PAIRS 4             // (n,c) pairs per block (one per wave in apply)

// torso joints {0,1,2,3,20} as a bitmask
#define TORSO_MASK 0x10000Fu

// output joint position -> source joint (concat order: TORSO, LH, LL, RH, RL)
__constant__ int SRC_J[25] = {0,1,2,3,20,  8,9,10,11,23,24,  16,17,18,19,  4,5,6,7,21,22,  12,13,14,15};
// output joint position -> group index
__constant__ int GRP_J[25] = {0,0,0,0,0,   1,1,1,1,1,1,      2,2,2,2,      3,3,3,3,3,3,   4,4,4,4};

// ---------------- Kernel A: torso pooling, fully coalesced float4 reads ----------------
// (unchanged from R2 — proven correct)
__global__ void pool_kernel(const float4* __restrict__ x4,
                            float* __restrict__ avg_out,
                            float* __restrict__ max_out) {
    const int wave = threadIdx.x >> 6;
    const int lane = threadIdx.x & 63;
    const int pair = blockIdx.x * 4 + wave;      // n*C + c
    const int base4 = pair * ROWF4;

    float s = 0.0f;
    float m = -3.4e38f;
    for (int i = lane; i < ROWF4; i += 64) {
        float4 v = x4[base4 + i];
        const int e = 4 * i;
        int j = e % 25;
        float vals[4] = {v.x, v.y, v.z, v.w};
        #pragma unroll
        for (int k = 0; k < 4; ++k) {
            int jj = j + k;
            if (jj >= 25) jj -= 25;
            if ((TORSO_MASK >> jj) & 1u) {
                s += vals[k];
                m = fmaxf(m, vals[k]);
            }
        }
    }
    #pragma unroll
    for (int off = 32; off >= 1; off >>= 1) {
        s += __shfl_xor(s, off, 64);
        m = fmaxf(m, __shfl_xor(m, off, 64));
    }
    if (lane == 0) {
        avg_out[pair] = s * (1.0f / (TT * 5));
        max_out[pair] = m;
    }
}

// ---------------- Kernel B: gate MLPs (unchanged from R2 — proven correct) ----------------
__global__ void gates_kernel(const float* __restrict__ avg_in,
                             const float* __restrict__ max_in,
                             const float* __restrict__ W1s,   // (5,16,256)
                             const float* __restrict__ b1s,   // (5,16)
                             const float* __restrict__ W2s,   // (5,256,16)
                             const float* __restrict__ b2s,   // (5,256)
                             float* __restrict__ gates) {     // (N,5,256)
    __shared__ float4 sAvg[CC / 4];
    __shared__ float4 sMax[CC / 4];
    __shared__ float sHA[NG * HID];
    __shared__ float sHM[NG * HID];

    const int n = blockIdx.x;
    const int tid = threadIdx.x;

    if (tid < 64)       sAvg[tid]      = reinterpret_cast<const float4*>(avg_in + n * CC)[tid];
    else if (tid < 128) sMax[tid - 64] = reinterpret_cast<const float4*>(max_in + n * CC)[tid - 64];
    __syncthreads();

    if (tid < 2 * NG * HID) {              // 160 threads
        const int type = tid / (NG * HID); // 0 = avg, 1 = max
        const int rem  = tid % (NG * HID); // f*16 + j
        const float4* p = type ? sMax : sAvg;
        const float4* w = reinterpret_cast<const float4*>(W1s + rem * CC);
        float h = b1s[rem];
        #pragma unroll 8
        for (int c4 = 0; c4 < CC / 4; ++c4) {
            float4 a = w[c4], b = p[c4];
            h += a.x * b.x + a.y * b.y + a.z * b.z + a.w * b.w;
        }
        h = fmaxf(h, 0.0f);
        if (type) sHM[rem] = h; else sHA[rem] = h;
    }
    __syncthreads();

    const int c = tid;
    #pragma unroll
    for (int f = 0; f < NG; ++f) {
        const float4* w2 = reinterpret_cast<const float4*>(W2s + (f * CC + c) * HID);
        float g = 2.0f * b2s[f * CC + c];
        #pragma unroll
        for (int j4 = 0; j4 < HID / 4; ++j4) {
            float4 w = w2[j4];
            const int jb = f * HID + j4 * 4;
            g += w.x * (sHA[jb + 0] + sHM[jb + 0]);
            g += w.y * (sHA[jb + 1] + sHM[jb + 1]);
            g += w.z * (sHA[jb + 2] + sHM[jb + 2]);
            g += w.w * (sHA[jb + 3] + sHM[jb + 3]);
        }
        gates[(n * NG + f) * CC + c] = 1.0f / (1.0f + expf(-g));
    }
}

// ---------------- Kernel C: LDS-staged scale + joint permutation, v3 ----------------
// LDS-pipe diet: per wave-iteration 1 ds_write_b128 + 4 ds_read_b32 (data)
// + 1 ds_read_b64 (packed LUT). Gates live in registers (wave = pair),
// selected by a cndmask chain (VALU has headroom: 13% busy in R1 profile).
__global__ void apply_kernel(const float4* __restrict__ x4,
                             const float* __restrict__ gates,
                             float4* __restrict__ out4) {
    __shared__ __align__(16) float xt[PAIRS * ROWF];   // 25.6 KB
    __shared__ uint2 sLut4[VV];                        // packed perm entries

    const int tid  = threadIdx.x;
    const int b    = blockIdx.x;
    const int w    = tid >> 6;       // wave index = local pair index
    const int lane = tid & 63;
    const int base4 = b * PAIRS * ROWF4;

    // coalesced stage of PAIRS row-blocks into LDS (25 iters, b128 writes)
    #pragma unroll
    for (int i = tid; i < PAIRS * ROWF4; i += 256) {
        reinterpret_cast<float4*>(xt)[i] = x4[base4 + i];
    }

    // Build packed LUT: entry[p0] holds, for output positions p0..p0+3,
    // 16-bit fields: (SRC_J[p] + 25*row_wrap) | (GRP_J[p] << 8).
    // Row-wrap (p0+j crossing 25) is folded into the source offset.
    if (tid < VV) {
        unsigned lo = 0, hi = 0;
        #pragma unroll
        for (int j = 0; j < 4; ++j) {
            const int pp   = tid + j;
            const int wrap = (pp >= VV) ? 1 : 0;
            const int pm   = pp - VV * wrap;
            const unsigned e = (unsigned)(SRC_J[pm] + VV * wrap) | ((unsigned)GRP_J[pm] << 8);
            if (j < 2) lo |= e << (16 * j);
            else       hi |= e << (16 * (j - 2));
        }
        sLut4[tid] = make_uint2(lo, hi);
    }

    // This wave's pair -> 5 gates in registers (wave-uniform addresses,
    // same-address lane loads broadcast from one L2 line).
    const int pair = b * PAIRS + w;          // n*C + c
    const int n = pair >> 8;
    const int c = pair & (CC - 1);
    const float g0 = gates[(n * NG + 0) * CC + c];
    const float g1 = gates[(n * NG + 1) * CC + c];
    const float g2 = gates[(n * NG + 2) * CC + c];
    const float g3 = gates[(n * NG + 3) * CC + c];
    const float g4 = gates[(n * NG + 4) * CC + c];

    __syncthreads();

    const float* lrow = xt + w * ROWF;
    #pragma unroll
    for (int k = 0; k < 7; ++k) {
        const int il = 64 * k + lane;        // float4 index within this pair
        if (il < ROWF4) {
            const int e0   = 4 * il;             // first output element index
            const int row0 = e0 / VV;            // compiler emits magic-mul
            const int p0   = e0 - row0 * VV;     // output position in row
            const uint2 lut = sLut4[p0];         // 1 ds_read_b64 for 4 elements
            float r[4];
            #pragma unroll
            for (int j = 0; j < 4; ++j) {
                const unsigned half   = ((j < 2) ? lut.x : lut.y) >> (16 * (j & 1));
                const unsigned srcoff = half & 63u;          // src + 25*wrap
                const unsigned grp    = (half >> 8) & 7u;
                float gt = g0;                                // cndmask chain
                gt = (grp >= 1u) ? g1 : gt;
                gt = (grp >= 2u) ? g2 : gt;
                gt = (grp >= 3u) ? g3 : gt;
                gt = (grp >= 4u) ? g4 : gt;
                r[j] = lrow[row0 * VV + (int)srcoff] * gt;   // 1 ds_read_b32
            }
            out4[base4 + w * ROWF4 + il] = make_float4(r[0], r[1], r[2], r[3]);
        }
    }
}

extern "C" void kernel_launch(void* const* d_in, const int* in_sizes, int n_in,
                              void* d_out, int out_size, void* d_ws, size_t ws_size,
                              hipStream_t stream) {
    const float* x   = (const float*)d_in[0];
    const float* W1s = (const float*)d_in[1];
    const float* b1s = (const float*)d_in[2];
    const float* W2s = (const float*)d_in[3];
    const float* b2s = (const float*)d_in[4];

    float* avg   = (float*)d_ws;                  // N*C
    float* mx    = avg + NB * CC;                 // N*C
    float* gates = mx + NB * CC;                  // N*5*C

    // Kernel A: 16384 (n,c) pairs, one wave each, 4 waves/block -> 4096 blocks
    pool_kernel<<<(NB * CC) / 4, 256, 0, stream>>>(
        (const float4*)x, avg, mx);

    // Kernel B: one block per n
    gates_kernel<<<NB, CC, 0, stream>>>(avg, mx, W1s, b1s, W2s, b2s, gates);

    // Kernel C: PAIRS pairs per block -> 4096 blocks
    apply_kernel<<<(NB * CC) / PAIRS, 256, 0, stream>>>(
        (const float4*)x, gates, (float4*)d_out);
}